// Round 8
// baseline (391.312 us; speedup 1.0000x reference)
//
#include <hip/hip_runtime.h>
#include <hip/hip_bf16.h>

#define B_ROWS 8192
#define DIM 512

typedef __bf16 bf16x8 __attribute__((ext_vector_type(8)));
typedef float f32x4 __attribute__((ext_vector_type(4)));

__device__ inline ushort f2bf(float x) {
    __hip_bfloat16 h = __float2bfloat16(x);
    return __builtin_bit_cast(ushort, h);
}

// --- Kernel 1: row-normalize A and B, cast to bf16 into workspace ---
__global__ __launch_bounds__(256) void norm_kernel(const float* __restrict__ A,
                                                   const float* __restrict__ Bf,
                                                   ushort* __restrict__ An,
                                                   ushort* __restrict__ Bn) {
    int gw = (blockIdx.x * 256 + threadIdx.x) >> 6;   // 0..16383
    int lane = threadIdx.x & 63;
    const float* src;
    ushort* dst;
    if (gw < B_ROWS) {
        src = A + (size_t)gw * DIM;
        dst = An + (size_t)gw * DIM;
    } else {
        src = Bf + (size_t)(gw - B_ROWS) * DIM;
        dst = Bn + (size_t)(gw - B_ROWS) * DIM;
    }
    const float4* s4 = (const float4*)src;
    float4 v0 = s4[lane * 2];
    float4 v1 = s4[lane * 2 + 1];
    float ss = v0.x * v0.x + v0.y * v0.y + v0.z * v0.z + v0.w * v0.w
             + v1.x * v1.x + v1.y * v1.y + v1.z * v1.z + v1.w * v1.w;
#pragma unroll
    for (int m = 32; m >= 1; m >>= 1) ss += __shfl_xor(ss, m, 64);
    float scale = 1.0f / fmaxf(sqrtf(ss), 1e-8f);
    union { ushort us[8]; uint4 q; } o;
    o.us[0] = f2bf(v0.x * scale); o.us[1] = f2bf(v0.y * scale);
    o.us[2] = f2bf(v0.z * scale); o.us[3] = f2bf(v0.w * scale);
    o.us[4] = f2bf(v1.x * scale); o.us[5] = f2bf(v1.y * scale);
    o.us[6] = f2bf(v1.z * scale); o.us[7] = f2bf(v1.w * scale);
    ((uint4*)dst)[lane] = o.q;
}

// --- Kernel 2: 256x256-tile bf16 NT-GEMM, 8-phase K-loop (unchanged from
//     round 7), NEW epilogue: LDS-repack -> float4 coalesced C stores with
//     fused exp row-sum; XCD-swizzled 1D grid. ---
#define GLDS(src, dst) __builtin_amdgcn_global_load_lds( \
    (const __attribute__((address_space(1))) unsigned int*)(src), \
    (__attribute__((address_space(3))) unsigned int*)(dst), 16, 0, 0)

#define STG(bufv, ab, PTR, doff, ktv) do {                                   \
    GLDS((PTR) + (ktv) * 64,      L + (((bufv)*2 + (ab))*2 + 0)*8192 + (doff)); \
    GLDS((PTR) + (ktv) * 64 + 32, L + (((bufv)*2 + (ab))*2 + 1)*8192 + (doff)); } while (0)

#define BARRIER() asm volatile("s_barrier" ::: "memory")

__global__ __launch_bounds__(512, 2) void gemm_kernel(
    const ushort* __restrict__ An, const ushort* __restrict__ Bn,
    float* __restrict__ C, float* __restrict__ rowpart,
    const float* __restrict__ wp, const float* __restrict__ bp) {
    // [buf][A,B][kkhalf][256 rows * 32 k] bf16 = 128 KB total.
    __shared__ ushort lds[2][2][2][8192];
    ushort* L = &lds[0][0][0][0];

    const int t = threadIdx.x;
    // XCD-aware bijective swizzle: grid 1024 = 8 XCDs x 128 contiguous tiles.
    const int bid = blockIdx.x;
    const int orig = ((bid & 7) << 7) | (bid >> 3);
    const int by = orig >> 5, bx = orig & 31;
    const int brow = by * 256;
    const int bcol = bx * 256;
    const int wid = t >> 6, lane = t & 63;
    const int wr = wid >> 2, wc = wid & 3;   // 2 x 4 wave grid, wave tile 128x64
    const int fr = lane & 15;
    const int fhi = lane >> 4;

    // ---- staging addressing (quadrant-matched halves, per-wave-linear) ----
    const int schunk8 = ((t & 3) ^ ((t >> 3) & 3)) * 8;  // source chunk (swizzle)
    const int srowAa = (t >> 8) * 128 + ((t >> 2) & 63);
    const int srowBa = (t >> 7) * 64 + ((t >> 2) & 31);
    const ushort* pAa = An + (size_t)(brow + srowAa) * DIM + schunk8;
    const ushort* pAb = An + (size_t)(brow + srowAa + 64) * DIM + schunk8;
    const ushort* pBa = Bn + (size_t)(bcol + srowBa) * DIM + schunk8;
    const ushort* pBb = Bn + (size_t)(bcol + srowBa + 32) * DIM + schunk8;
    const int dAa = t * 8 + (t >> 8) * 2048;
    const int dAb = dAa + 2048;
    const int dBa = t * 8 + (t >> 7) * 1024;
    const int dBb = dBa + 1024;

    // stored chunk c holds global chunk c ^ ((row>>1)&3); rows are *+16m+fr so
    // (row>>1)&3 == (fr>>1)&3 always.
    const int rchunk8 = (fhi ^ ((fr >> 1) & 3)) * 8;

    f32x4 acc[8][4];
#pragma unroll
    for (int i = 0; i < 8; i++)
#pragma unroll
        for (int j = 0; j < 4; j++) acc[i][j] = (f32x4){0.f, 0.f, 0.f, 0.f};

    bf16x8 af[4][2], b0[2][2], b1[2][2];

    auto rdA = [&](int buf, int mb) {
#pragma unroll
        for (int i = 0; i < 4; ++i)
#pragma unroll
            for (int kk = 0; kk < 2; ++kk)
                af[i][kk] = *(const bf16x8*)(L + ((buf * 2 + 0) * 2 + kk) * 8192
                            + (wr * 128 + (mb + i) * 16 + fr) * 32 + rchunk8);
    };
    auto rdB = [&](bf16x8 (&b)[2][2], int buf, int nb) {
#pragma unroll
        for (int j = 0; j < 2; ++j)
#pragma unroll
            for (int kk = 0; kk < 2; ++kk)
                b[j][kk] = *(const bf16x8*)(L + ((buf * 2 + 1) * 2 + kk) * 8192
                           + (wc * 64 + (nb + j) * 16 + fr) * 32 + rchunk8);
    };
    auto mfma16 = [&](bf16x8 (&b)[2][2], int mb, int nb) {
        __builtin_amdgcn_sched_barrier(0);
        __builtin_amdgcn_s_setprio(1);
#pragma unroll
        for (int i = 0; i < 4; ++i)
#pragma unroll
            for (int j = 0; j < 2; ++j)
#pragma unroll
                for (int kk = 0; kk < 2; ++kk)
                    acc[mb + i][nb + j] = __builtin_amdgcn_mfma_f32_16x16x32_bf16(
                        af[i][kk], b[j][kk], acc[mb + i][nb + j], 0, 0, 0);
        __builtin_amdgcn_s_setprio(0);
        __builtin_amdgcn_sched_barrier(0);
    };

    // ---- prologue: stage K-tile 0 fully, full drain ----
    STG(0, 0, pAa, dAa, 0);
    STG(0, 1, pBa, dBa, 0);
    STG(0, 0, pAb, dAb, 0);
    STG(0, 1, pBb, dBb, 0);
    asm volatile("s_waitcnt vmcnt(0)\n\ts_barrier" ::: "memory");

#pragma unroll
    for (int kt = 0; kt < 8; ++kt) {
        const int cur = kt & 1, nxt = cur ^ 1;
        // ---- P1: quadrant m0-3 x n0-1 ----
        if (kt < 7) STG(nxt, 0, pAa, dAa, kt + 1);
        rdA(cur, 0);
        rdB(b0, cur, 0);
        BARRIER();
        mfma16(b0, 0, 0);
        if (kt == 7) { asm volatile("s_waitcnt vmcnt(0)\n\ts_barrier" ::: "memory"); }
        else         { asm volatile("s_waitcnt vmcnt(2)\n\ts_barrier" ::: "memory"); }
        // ---- P2: m0-3 x n2-3 ----
        if (kt < 7) STG(nxt, 1, pBa, dBa, kt + 1);
        rdB(b1, cur, 2);
        BARRIER();
        mfma16(b1, 0, 2);
        BARRIER();
        // ---- P3: m4-7 x n2-3 ----
        if (kt < 7) STG(nxt, 0, pAb, dAb, kt + 1);
        rdA(cur, 4);
        BARRIER();
        mfma16(b1, 4, 2);
        BARRIER();
        // ---- P4: m4-7 x n0-1 (b0 held from P1) ----
        if (kt < 7) STG(nxt, 1, pBb, dBb, kt + 1);
        BARRIER();
        mfma16(b0, 4, 0);
        if (kt < 7) { asm volatile("s_waitcnt vmcnt(4)\n\ts_barrier" ::: "memory"); }
        else        { BARRIER(); }
    }

    // ---- epilogue: LDS repack -> coalesced float4 stores + fused exp rowsum.
    // Two phases of 4 m-values each; per phase the 128 rows x 256 cols of f32
    // fill the whole 128 KB LDS. XOR swizzles keep LDS <=2-way on both sides.
    __syncthreads();   // all K-loop LDS reads retired
    const float w = wp[0], bb = bp[0];
    const float M = fabsf(w) + fabsf(bb);   // |s| <= M bounds every score
    float* FL = (float*)L;                  // [128][256] f32

    const int rrow = t >> 2;                // reader row 0..127
    const int rx = (rrow >> 2) & 3;         // fhi bits of that row
    const int xr = rx ^ (rrow & 1);         // read-side XOR (matches write side)
    const int rc0 = t & 3;                  // c4 = rc0 + 4*i
    const int rwr = rrow >> 6, rwithin = rrow & 63;

#pragma unroll
    for (int ph = 0; ph < 2; ++ph) {
        // write: m in [4ph, 4ph+4)
#pragma unroll
        for (int mm = 0; mm < 4; ++mm) {
            const int m = 4 * ph + mm;
#pragma unroll
            for (int r = 0; r < 4; ++r) {
                const int wrow = wr * 64 + mm * 16 + fhi * 4 + r;  // 0..127
                const int xw = (fhi ^ (r & 1)) << 4;
#pragma unroll
                for (int n = 0; n < 4; ++n) {
                    const int col = (wc * 64 + n * 16 + fr) ^ xw;
                    FL[wrow * 256 + col] = fmaf(w, acc[m][n][r], bb);
                }
            }
        }
        __syncthreads();
        // read + coalesced store + exp row-sum (thread owns 1 row x 64 cols)
        const int rowfull = rwr * 128 + 64 * ph + rwithin;
        const size_t grow = (size_t)(brow + rowfull);
        float* crow = C + grow * B_ROWS + bcol;
        float psum = 0.f;
#pragma unroll
        for (int i = 0; i < 16; ++i) {
            const int c4 = rc0 + 4 * i;
            const int c4s = c4 ^ (xr << 2);
            f32x4 v = *(const f32x4*)&FL[rrow * 256 + c4s * 4];
            *(f32x4*)(crow + 4 * c4) = v;
            psum += __expf(v[0] - M) + __expf(v[1] - M)
                  + __expf(v[2] - M) + __expf(v[3] - M);
        }
        psum += __shfl_xor(psum, 1, 64);
        psum += __shfl_xor(psum, 2, 64);
        if (rc0 == 0) rowpart[(size_t)bx * B_ROWS + grow] = psum;
        __syncthreads();   // before next phase overwrites LDS
    }
}

// --- Kernel 3: loss = -mean(diag(s) - M - log(rowsum)) ---
__global__ __launch_bounds__(256) void loss_kernel(const float* __restrict__ C,
                                                   const float* __restrict__ rowpart,
                                                   const float* __restrict__ wp,
                                                   const float* __restrict__ bp,
                                                   float* __restrict__ out0) {
    __shared__ float sred[4];
    const int row = blockIdx.x * 256 + threadIdx.x;
    float rs = 0.f;
#pragma unroll
    for (int j = 0; j < 32; ++j) rs += rowpart[(size_t)j * B_ROWS + row];
    const float M = fabsf(wp[0]) + fabsf(bp[0]);
    const float sii = C[(size_t)row * B_ROWS + row];
    float v = sii - M - __logf(rs);
#pragma unroll
    for (int msk = 32; msk >= 1; msk >>= 1) v += __shfl_xor(v, msk, 64);
    if ((threadIdx.x & 63) == 0) sred[threadIdx.x >> 6] = v;
    __syncthreads();
    if (threadIdx.x == 0) {
        float tot = sred[0] + sred[1] + sred[2] + sred[3];
        atomicAdd(out0, -tot / (float)B_ROWS);
    }
}

extern "C" void kernel_launch(void* const* d_in, const int* in_sizes, int n_in,
                              void* d_out, int out_size, void* d_ws, size_t ws_size,
                              hipStream_t stream) {
    const float* A  = (const float*)d_in[1];
    const float* Bf = (const float*)d_in[2];
    const float* wp = (const float*)d_in[3];
    const float* bp = (const float*)d_in[4];
    float* out = (float*)d_out;  // [0] = loss, [1..] = cos_score row-major

    ushort* An = (ushort*)d_ws;
    ushort* Bn = An + (size_t)B_ROWS * DIM;
    float* rowpart = (float*)((char*)d_ws + (size_t)2 * B_ROWS * DIM * sizeof(ushort));

    hipMemsetAsync(d_out, 0, sizeof(float), stream);  // zero the loss slot
    norm_kernel<<<dim3(16384 * 64 / 256), 256, 0, stream>>>(A, Bf, An, Bn);
    gemm_kernel<<<dim3(1024), 512, 0, stream>>>(An, Bn, out + 1, rowpart, wp, bp);
    loss_kernel<<<B_ROWS / 256, 256, 0, stream>>>(out + 1, rowpart, wp, bp, out);
}